// Round 2
// baseline (83.847 us; speedup 1.0000x reference)
//
#include <hip/hip_runtime.h>

// PolyLinear via fused MFMA GEMM.
//
// Reformulation with augmented features x_aug[33] (x[32] = 1):
//   out[i] = sum_{p=(a<=b), a,b in [0,33)} x_a(i)*x_b(i) * S_p(i)
//   S_p(i) = sum_c Wm[p][c] * x_aug[c](i)
// where Wm[p][c] folds deg-3 (c in [b,32)), deg-2 (c==32, b<32),
// deg-1 (pair (a,32), c==32), and the bias (pair (32,32), c==32).
//
// Phase 1 (S) = skinny GEMM via v_mfma_f32_32x32x16_bf16:
//   A = Wm (M=576 pairs, 18 m-tiles), B = x_aug^T (N=32 batch rows/block),
//   K = 48 (3 chunks of 16). C layout (HW-verified): col=lane&31 (batch row),
//   row=(reg&3)+8*(reg>>2)+4*(lane>>5) (pair offset).
// Because col == the lane's own batch row, the epilogue multiplier
// x_a*x_b uses the lane's private x[33] registers with COMPILE-TIME
// indices (p is constexpr inside the h = lane>>5 branch).
//
// W is delivered as VMEM A-fragments from a 54 KB table in d_ws (built by a
// prep kernel each call; ws re-poisoned every launch so prep writes all of it).
// No scalar-load W delivery, no big unroll (code ~10 KB), LDS only for the
// final 8-way cross-wave reduction.

typedef __attribute__((ext_vector_type(8))) short short8;
typedef __attribute__((ext_vector_type(16))) float f32x16;

#define NT 18  // m-tiles of 32 pairs: 576 >= 561
#define WT_ELEMS (NT * 3 * 2 * 32 * 8)  // [t][kc][h][m][j] = 27648 shorts

// ---- index math (verified in round-1 kernel, absmax 2e-3) ----
__host__ __device__ constexpr int off2(int a, int b) {
    return 32 + 32 * a - (a * (a - 1)) / 2 + (b - a);
}

__device__ inline int off3_rt(int a, int b, int c) {
    const int g3[32] = {
        0,    528,  1024, 1489, 1924, 2330, 2708, 3059,
        3384, 3684, 3960, 4213, 4444, 4654, 4844, 5015,
        5168, 5304, 5424, 5529, 5620, 5698, 5764, 5819,
        5864, 5900, 5928, 5949, 5964, 5974, 5980, 5983};
    return 560 + g3[a] + 32 * (b - a) - ((b * (b - 1)) / 2 - (a * (a - 1)) / 2) + (c - b);
}

// pair p (lex order over a<=b, 33 features) -> (a, b); constexpr for epilogue
__host__ __device__ constexpr int cpa(int p) {
    int a = 0, rem = p;
    while (rem >= 33 - a) { rem -= 33 - a; a++; }
    return a;
}
__host__ __device__ constexpr int cpb(int p) {
    int a = 0, rem = p;
    while (rem >= 33 - a) { rem -= 33 - a; a++; }
    return a + rem;
}

__device__ inline unsigned short f2bf(float f) {
    union { float f; unsigned u; } v;
    v.f = f;
    unsigned u = v.u + (0x7FFFu + ((v.u >> 16) & 1u));  // round-to-nearest-even
    return (unsigned short)(u >> 16);
}

// ---- prep: build Wm in A-fragment layout [t][kc][h][m][j], bf16 ----
__global__ __launch_bounds__(256) void prep_wt(const float* __restrict__ W,
                                               const float* __restrict__ Bp,
                                               unsigned short* __restrict__ wt) {
    int e = blockIdx.x * 256 + threadIdx.x;
    if (e >= WT_ELEMS) return;
    int j = e % 8, e2 = e / 8;
    int m = e2 % 32; e2 /= 32;
    int h = e2 % 2;  e2 /= 2;
    int kc = e2 % 3; e2 /= 3;
    int t = e2;
    int p = t * 32 + m;
    int c = kc * 16 + h * 8 + j;
    float v = 0.0f;
    if (p < 561 && c <= 32) {
        int a = 0, rem = p;
        while (rem >= 33 - a) { rem -= 33 - a; a++; }
        int b = a + rem;
        if (c >= b) {
            if (c == 32) {
                if (b == 32) v = (a == 32) ? Bp[0] : W[a];  // bias / deg-1
                else         v = W[off2(a, b)];             // deg-2
            } else {
                v = W[off3_rt(a, b, c)];                    // deg-3
            }
        }
    }
    wt[e] = f2bf(v);
}

// ---- epilogue: racc += x[a]*x[b] * C[R], compile-time (a,b) ----
template <int T, int H, int R>
__device__ __forceinline__ void epi(const float (&x)[33], const f32x16& c, float& racc) {
    if constexpr (R < 16) {
        constexpr int p = T * 32 + (R & 3) + 8 * (R >> 2) + 4 * H;
        if constexpr (p < 561) {
            constexpr int a = cpa(p);
            constexpr int b = cpb(p);
            racc = __builtin_fmaf(x[a] * x[b], c[R], racc);
        }
        epi<T, H, R + 1>(x, c, racc);
    }
}

template <int T>
__device__ __forceinline__ void tile(const unsigned short* __restrict__ wtl,
                                     const float (&x)[33],
                                     const short8& b0, const short8& b1, const short8& b2,
                                     float& racc, int h) {
    // A-fragments: lane-l address folds to wt + l*8 + (T*3+kc)*512
    short8 a0 = *(const short8*)(wtl + (T * 3 + 0) * 512);
    short8 a1 = *(const short8*)(wtl + (T * 3 + 1) * 512);
    short8 a2 = *(const short8*)(wtl + (T * 3 + 2) * 512);
    f32x16 c = {0.0f, 0.0f, 0.0f, 0.0f, 0.0f, 0.0f, 0.0f, 0.0f,
                0.0f, 0.0f, 0.0f, 0.0f, 0.0f, 0.0f, 0.0f, 0.0f};
    c = __builtin_amdgcn_mfma_f32_32x32x16_bf16(a0, b0, c, 0, 0, 0);
    c = __builtin_amdgcn_mfma_f32_32x32x16_bf16(a1, b1, c, 0, 0, 0);
    c = __builtin_amdgcn_mfma_f32_32x32x16_bf16(a2, b2, c, 0, 0, 0);
    if (h == 0) epi<T, 0, 0>(x, c, racc);
    else        epi<T, 1, 0>(x, c, racc);
}

template <int T0, int T1>
__device__ __forceinline__ void tiles(const unsigned short* __restrict__ wtl,
                                      const float (&x)[33],
                                      const short8& b0, const short8& b1, const short8& b2,
                                      float& racc, int h) {
    if constexpr (T0 < T1) {
        tile<T0>(wtl, x, b0, b1, b2, racc, h);
        tiles<T0 + 1, T1>(wtl, x, b0, b1, b2, racc, h);
    }
}

// Block: 256 threads = 4 waves, 32 batch rows. Waves split the 18 m-tiles
// {5,4,5,4}; 8 partials per row (4 waves x 2 half-wave groups) reduced in LDS.
__global__ __launch_bounds__(256) void PolyLinear_40218073760341_kernel(
    const float* __restrict__ X, const unsigned short* __restrict__ wt,
    float* __restrict__ out) {
    const int tid  = threadIdx.x;
    const int lane = tid & 63;
    const int wave = tid >> 6;
    const int h    = (tid >> 5) & 1;
    const int col  = tid & 31;
    const long row = (long)blockIdx.x * 32 + col;

    float x[33];
    const float4* xr = (const float4*)(X + row * 32);
#pragma unroll
    for (int i = 0; i < 8; ++i) {
        float4 v = xr[i];
        x[4 * i + 0] = v.x; x[4 * i + 1] = v.y;
        x[4 * i + 2] = v.z; x[4 * i + 3] = v.w;
    }
    x[32] = 1.0f;

    // B-fragments from own registers: B[k = kc*16 + h*8 + j][n = col] = x[k]
    short8 b0, b1, b2;
#pragma unroll
    for (int j = 0; j < 8; ++j) {
        b0[j] = (short)f2bf(h ? x[8 + j]  : x[j]);
        b1[j] = (short)f2bf(h ? x[24 + j] : x[16 + j]);
        b2[j] = 0;
    }
    b2[0] = h ? (short)0 : (short)0x3F80;  // k=32 -> x_aug=1.0, k>32 -> 0

    const unsigned short* wtl = wt + lane * 8;

    float racc = 0.0f;
    if (wave == 0)      tiles<0, 5>(wtl, x, b0, b1, b2, racc, h);
    else if (wave == 1) tiles<5, 9>(wtl, x, b0, b1, b2, racc, h);
    else if (wave == 2) tiles<9, 14>(wtl, x, b0, b1, b2, racc, h);
    else                tiles<14, 18>(wtl, x, b0, b1, b2, racc, h);

    __shared__ float red[256];
    red[tid] = racc;
    __syncthreads();
    if (tid < 32) {
        float s = 0.0f;
#pragma unroll
        for (int k = 0; k < 8; ++k) s += red[k * 32 + tid];
        out[(long)blockIdx.x * 32 + tid] = s;
    }
}

extern "C" void kernel_launch(void* const* d_in, const int* in_sizes, int n_in,
                              void* d_out, int out_size, void* d_ws, size_t ws_size,
                              hipStream_t stream) {
    const float* X  = (const float*)d_in[0];  // (32768, 32) fp32
    const float* W  = (const float*)d_in[1];  // (6544,) fp32
    const float* Bp = (const float*)d_in[2];  // (1,) fp32
    float* out = (float*)d_out;
    unsigned short* wt = (unsigned short*)d_ws;  // 54 KB A-fragment table

    prep_wt<<<(WT_ELEMS + 255) / 256, 256, 0, stream>>>(W, Bp, wt);

    const int rows = in_sizes[0] / 32;  // 32768
    PolyLinear_40218073760341_kernel<<<rows / 32, 256, 0, stream>>>(X, wt, out);
}